// Round 22
// baseline (1022.521 us; speedup 1.0000x reference)
//
#include <hip/hip_runtime.h>
#include <hip/hip_bf16.h>
#include <math.h>

#define B_   16
#define S_   512
#define E_   1024
#define H_   16
#define D_   64
#define NL_  6
#define OUT_ 10
#define M_   (B_*S_)

typedef short short8 __attribute__((ext_vector_type(8)));
typedef float f32x4 __attribute__((ext_vector_type(4)));
typedef int   int4v __attribute__((ext_vector_type(4)));
typedef unsigned short ushort4v __attribute__((ext_vector_type(4)));

typedef const __attribute__((address_space(1))) unsigned int* gas1_t;
typedef __attribute__((address_space(3))) unsigned int* las3_t;
#define GLD16(g,l) __builtin_amdgcn_global_load_lds((gas1_t)(g), (las3_t)(l), 16, 0, 0)

static __device__ __forceinline__ float bf2f(unsigned short u){
  union { unsigned int i; float f; } v; v.i = ((unsigned int)u) << 16; return v.f;
}
// native bf16 convert (RNE) — hw cvt on gfx950
static __device__ __forceinline__ unsigned short f2bf(float f){
  union { __hip_bfloat16 h; unsigned short u; } v;
  v.h = __float2bfloat16(f);
  return v.u;
}
static __device__ __forceinline__ f32x4 mfma16(short8 a, short8 b, f32x4 c){
  return __builtin_amdgcn_mfma_f32_16x16x32_bf16(a, b, c, 0, 0, 0);
}

// ---------------- code writer (f32 output) ----------------
__global__ __launch_bounds__(192)
void code_k(float* __restrict__ out, float code)
{
  int t = threadIdx.x;
  if (t < B_*OUT_) out[t] = code;
}

// ---------------- weight transpose + f32->bf16: wT[n][k] = bf16(w[k][n]) ----------------
__global__ __launch_bounds__(256)
void transpose_k(const float* __restrict__ w0, const float* __restrict__ w1,
                 const float* __restrict__ w2, const float* __restrict__ w3,
                 unsigned short* __restrict__ wT)
{
  const float* w = blockIdx.z==0 ? w0 : blockIdx.z==1 ? w1 : blockIdx.z==2 ? w2 : w3;
  unsigned short* o = wT + (size_t)blockIdx.z * E_ * E_;
  __shared__ unsigned short tl[64][65];
  int n0 = blockIdx.x*64, k0 = blockIdx.y*64;
  int tx = threadIdx.x, ty = threadIdx.y;
  #pragma unroll
  for (int i = 0; i < 16; ++i)
    tl[ty + 4*i][tx] = f2bf(w[(size_t)(k0 + ty + 4*i)*E_ + n0 + tx]);
  __syncthreads();
  #pragma unroll
  for (int i = 0; i < 16; ++i)
    o[(size_t)(n0 + ty + 4*i)*E_ + k0 + tx] = tl[tx][ty + 4*i];
}

// ---------------- embedding + positional: x = 2*emb[tok] + pe[b,e]; bf16 out ----------------
__global__ __launch_bounds__(256)
void embed_k(const int* __restrict__ tok, const float* __restrict__ emb,
             unsigned short* __restrict__ x)
{
  int row = blockIdx.x;            // b*512+s
  int b = row >> 9;
  int tk = tok[row];
  tk = tk < 0 ? 0 : (tk > 15 ? 15 : tk);
  int e0 = threadIdx.x * 4;
  const float c0 = -9.210340371976184f / (float)E_;   // -ln(10000)/E
  f32x4 ev = *(const f32x4*)&emb[(size_t)tk * E_ + e0];
  ushort4v bb;
  #pragma unroll
  for (int i = 0; i < 4; ++i) {
    int e = e0 + i;
    float dv = expf((float)(e & ~1) * c0);
    float arg = (float)b * dv;
    float pe = (e & 1) ? cosf(arg) : sinf(arg);
    bb[i] = f2bf(2.0f * ev[i] + pe);
  }
  *(ushort4v*)&x[(size_t)row*E_ + e0] = bb;
}

// ---------------- 128x128 bf16 MFMA GEMM, BT = [N][K], T2 XOR-swizzled LDS ----------------
// MODE 0: QK (grid.y=16): wsel=nyt>>3 (0=Q,1=K), writes bf16 [B,H,S,D] at outq+wsel*M*E
// MODE 2: V  (grid.y=8):  writes TRANSPOSED bf16 [B,H,D,S] at outq
// MODE 1: FC (grid.y=8):  writes bf16 [M][E] at outq
template<int MODE>
__global__ __launch_bounds__(256)
void gemm_bt_k(const unsigned short* __restrict__ A,
               const unsigned short* __restrict__ BT,
               const float* __restrict__ biasA, const float* __restrict__ biasB,
               unsigned short* __restrict__ outq)
{
  __shared__ alignas(16) unsigned short SM[(MODE==2) ? 17408 : 16384];
  unsigned short* Al = SM;
  unsigned short* Bl = SM + 8192;
  int mt = blockIdx.x;
  int nyt = blockIdx.y;
  int wsel = (MODE == 0) ? (nyt >> 3) : 0;
  int nt   = (MODE == 0) ? (nyt & 7) : nyt;
  const unsigned short* Bp = BT + (size_t)wsel * E_ * E_ + (size_t)nt * 128 * E_;
  const float* bias = (MODE == 0) ? (wsel == 0 ? biasA : biasB) : biasA;
  int tid = threadIdx.x;
  int lane = tid & 63, wid = tid >> 6;
  int wr = wid >> 1, wc = wid & 1;
  int m0 = mt * 128;
  int lr = lane & 15, lk = lane >> 4;
  int lx = lr & 7;
  int c8 = tid & 7;
  int rbase = tid >> 3;                  // r = j*32 + rbase
  int c8s = c8 ^ (rbase & 7);
  f32x4 acc[4][4] = {};
  for (int kt = 0; kt < E_/64; ++kt) {
    #pragma unroll
    for (int j = 0; j < 4; ++j) {
      int r = j*32 + rbase;
      int idx = j*256 + tid;
      GLD16(A + (size_t)(m0 + r)*E_ + kt*64 + c8s*8, &Al[idx*8]);
      GLD16(Bp + (size_t)r*E_ + kt*64 + c8s*8, &Bl[idx*8]);
    }
    __syncthreads();
    #pragma unroll
    for (int kk = 0; kk < 2; ++kk) {
      int sA = ((kk*4 + lk) ^ lx) * 8;
      short8 af[4], bfr[4];
      #pragma unroll
      for (int mi = 0; mi < 4; ++mi)
        af[mi] = *(const short8*)&Al[(wr*64 + mi*16 + lr)*64 + sA];
      #pragma unroll
      for (int ni = 0; ni < 4; ++ni)
        bfr[ni] = *(const short8*)&Bl[(wc*64 + ni*16 + lr)*64 + sA];
      #pragma unroll
      for (int mi = 0; mi < 4; ++mi)
        #pragma unroll
        for (int ni = 0; ni < 4; ++ni)
          acc[mi][ni] = mfma16(af[mi], bfr[ni], acc[mi][ni]);
    }
    __syncthreads();
  }
  if (MODE == 2) {
    unsigned short* Ct = SM;
    #pragma unroll
    for (int ni = 0; ni < 4; ++ni) {
      int nl = wc*64 + ni*16 + lr;
      float bv = bias[nt*128 + nl];
      #pragma unroll
      for (int mi = 0; mi < 4; ++mi)
        #pragma unroll
        for (int j = 0; j < 4; ++j)
          Ct[nl*136 + wr*64 + mi*16 + lk*4 + j] = f2bf(acc[mi][ni][j] + bv);
    }
    __syncthreads();
    int dl = tid >> 1, half = tid & 1;
    int h = nt*2 + (dl >> 6), d = dl & 63;
    int bb = m0 >> 9, s0 = (m0 & 511) + half*64;
    unsigned short* gp = outq + (((size_t)(bb*H_ + h)*D_ + d)*S_ + s0);
    #pragma unroll
    for (int c = 0; c < 8; ++c)
      *(int4v*)(gp + c*8) = *(const int4v*)&Ct[dl*136 + half*64 + c*8];
  } else {
    unsigned short* Cl = SM;
    #pragma unroll
    for (int ni = 0; ni < 4; ++ni) {
      int n = nt*128 + wc*64 + ni*16 + lr;
      float bv = bias[n];
      #pragma unroll
      for (int mi = 0; mi < 4; ++mi)
        #pragma unroll
        for (int j = 0; j < 4; ++j)
          Cl[(wr*64 + mi*16 + lk*4 + j)*128 + wc*64 + ni*16 + lr] =
            f2bf(acc[mi][ni][j] + bv);
    }
    __syncthreads();
    int r = tid >> 1, half = tid & 1;
    int m = m0 + r;
    unsigned short* gp;
    if (MODE == 0) {
      int bb = m >> 9, s = m & 511;
      int h = nt*2 + half;
      gp = outq + (size_t)wsel*M_*E_ + (((size_t)(bb*H_ + h)*S_ + s)*D_);
    } else {
      gp = outq + (size_t)m*E_ + nt*128 + half*64;
    }
    const unsigned short* sp = &Cl[r*128 + half*64];
    #pragma unroll
    for (int c = 0; c < 8; ++c)
      *(int4v*)(gp + c*8) = *(const int4v*)(sp + c*8);
  }
}

// ---------------- flash attention: 1 strip/block, single-buffered K/V, 3 blocks/CU ----------------
// grid 1024 linear: bh = bid&255, strip = bid>>8 (co-XCD: strips of same bh are 256 apart).
// Per kt: stage K(128x64)+V(64x128) via global_load_lds -> barrier -> compute -> barrier.
// LDS: K 16KB + V 16KB + P 10KB = 43008 B -> 3 blocks/CU.
__global__ __launch_bounds__(512, 6)
void attn_k(const unsigned short* __restrict__ Q, const unsigned short* __restrict__ K,
            const unsigned short* __restrict__ VT, unsigned short* __restrict__ O)
{
  extern __shared__ unsigned short SMEM[];
  unsigned short* Kl = SMEM;              // [128][64] chunk-swizzled
  unsigned short* Vl = SMEM + 8192;       // [64][128] chunk-swizzled
  unsigned short* Pw = SMEM + 16384 + (threadIdx.x >> 6) * 640;
  int bid = blockIdx.x;
  int bh = bid & 255, strip = bid >> 8;
  int tid = threadIdx.x, lane = tid & 63, wid = tid >> 6;
  int lr = lane & 15, lk = lane >> 4;
  const unsigned short* Qb = Q + (size_t)bh * S_ * D_;
  const unsigned short* Kb = K + (size_t)bh * S_ * D_;
  const unsigned short* VTb = VT + (size_t)bh * S_ * D_;   // [d][s]
  int q0 = strip*128 + wid*16;
  short8 qf0 = *(const short8*)(Qb + (size_t)(q0 + lr)*D_ + lk*8);
  short8 qf1 = *(const short8*)(Qb + (size_t)(q0 + lr)*D_ + 32 + lk*8);
  f32x4 oacc[4] = {};
  float plsum[4] = {0.f,0.f,0.f,0.f};
  for (int kt = 0; kt < 4; ++kt) {
    #pragma unroll
    for (int j = 0; j < 2; ++j) {
      int idx = j*512 + tid;
      int r = idx >> 3, c8 = idx & 7;
      GLD16(Kb + (size_t)(kt*128 + r)*D_ + (c8 ^ (r & 7))*8, &Kl[idx*8]);
      int d = idx >> 4, c16 = idx & 15;
      GLD16(VTb + (size_t)d*S_ + kt*128 + (c16 ^ (d & 15))*8, &Vl[idx*8]);
    }
    __syncthreads();                     // drains staged gld_lds + publishes to all waves
    f32x4 sc[8];
    #pragma unroll
    for (int t = 0; t < 8; ++t) {
      const unsigned short* krow = &Kl[(t*16 + lr)*64];
      int a0 = ((lk     ^ (lr & 7)))*8;
      int a1 = (((4+lk) ^ (lr & 7)))*8;
      f32x4 s = {};
      s = mfma16(qf0, *(const short8*)(krow + a0), s);
      s = mfma16(qf1, *(const short8*)(krow + a1), s);
      #pragma unroll
      for (int j = 0; j < 4; ++j) s[j] = __expf(s[j] * 0.125f);
      sc[t] = s;
      #pragma unroll
      for (int j = 0; j < 4; ++j) plsum[j] += s[j];
    }
    #pragma unroll
    for (int c = 0; c < 4; ++c) {
      #pragma unroll
      for (int j = 0; j < 4; ++j) {
        Pw[(lk*4 + j)*40 + lr]      = f2bf(sc[2*c  ][j]);
        Pw[(lk*4 + j)*40 + 16 + lr] = f2bf(sc[2*c+1][j]);
      }
      asm volatile("s_waitcnt lgkmcnt(0)" ::: "memory");
      short8 pf = *(const short8*)&Pw[lr*40 + lk*8];
      #pragma unroll
      for (int dt = 0; dt < 4; ++dt) {
        int drow = dt*16 + lr;
        short8 vf = *(const short8*)&Vl[drow*128 + (((c*4 + lk) ^ lr))*8];
        oacc[dt] = mfma16(pf, vf, oacc[dt]);
      }
    }
    __syncthreads();                     // all reads done before next kt overwrites
  }
  float lsum[4];
  #pragma unroll
  for (int j = 0; j < 4; ++j) {
    float t = plsum[j];
    #pragma unroll
    for (int m = 1; m < 16; m <<= 1) t += __shfl_xor(t, m);
    lsum[j] = t;
  }
  #pragma unroll
  for (int dt = 0; dt < 4; ++dt)
    #pragma unroll
    for (int j = 0; j < 4; ++j)
      O[(size_t)bh*S_*D_ + (size_t)(q0 + lk*4 + j)*D_ + dt*16 + lr] =
        f2bf(oacc[dt][j] / lsum[j]);
}

// ---------------- residual + layernorm: wave-per-row, bf16 stream, no LDS ----------------
template<bool PERM>
__global__ __launch_bounds__(256)
void ln_k(const unsigned short* __restrict__ g, unsigned short* __restrict__ x,
          const float* __restrict__ gamma, const float* __restrict__ beta)
{
  int wid = threadIdx.x >> 6, lane = threadIdx.x & 63;
  int row = blockIdx.x * 4 + wid;
  int e0 = lane * 16;
  const unsigned short* gp;
  if (PERM) {
    int b = row >> 9, s = row & 511;
    int h = e0 >> 6, d = e0 & 63;       // d in {0,16,32,48}: 16-elem run stays in-head
    gp = g + (((size_t)(b*H_ + h)*S_) + s)*D_ + d;
  } else {
    gp = g + (size_t)row*E_ + e0;
  }
  unsigned short* xp = x + (size_t)row*E_ + e0;
  ushort4v gu[4], xu[4];
  #pragma unroll
  for (int i = 0; i < 4; ++i) { gu[i] = *(const ushort4v*)(gp + i*4); xu[i] = *(const ushort4v*)(xp + i*4); }
  float v[16];
  float sum = 0.f, sq = 0.f;
  #pragma unroll
  for (int i = 0; i < 16; ++i) {
    float t = bf2f(gu[i>>2][i&3]) + bf2f(xu[i>>2][i&3]);
    v[i] = t; sum += t; sq += t*t;
  }
  #pragma unroll
  for (int m = 1; m < 64; m <<= 1) { sum += __shfl_xor(sum, m); sq += __shfl_xor(sq, m); }
  float mu = sum * (1.0f/E_);
  float var = sq * (1.0f/E_) - mu*mu;
  float rsq = rsqrtf(var + 1e-5f);
  #pragma unroll
  for (int i = 0; i < 4; ++i) {
    ushort4v yb;
    #pragma unroll
    for (int j = 0; j < 4; ++j) {
      int e = e0 + i*4 + j;
      yb[j] = f2bf((v[i*4+j]-mu)*rsq*gamma[e] + beta[e]);
    }
    *(ushort4v*)(xp + i*4) = yb;
  }
}

// ---------------- output head (bf16 x input, f32 accum) ----------------
__global__ __launch_bounds__(256)
void outp_k(const unsigned short* __restrict__ x, const float* __restrict__ wout,
            float* __restrict__ part)
{
  int b = blockIdx.y;
  int chunk = blockIdx.x;
  int tid = threadIdx.x;
  float acc[OUT_] = {};
  const unsigned short* xr = x + (size_t)b * S_ * E_;
  for (int j = 0; j < 32; ++j) {
    int k = chunk*8192 + j*256 + tid;
    float xv = bf2f(xr[k]);
    const float* wr = wout + (size_t)k * OUT_;
    #pragma unroll
    for (int o = 0; o < OUT_; ++o) acc[o] += xv * wr[o];
  }
  #pragma unroll
  for (int o = 0; o < OUT_; ++o)
    #pragma unroll
    for (int m = 1; m < 64; m <<= 1) acc[o] += __shfl_xor(acc[o], m);
  __shared__ float red[4][OUT_];
  int lane = tid & 63, wid = tid >> 6;
  if (lane == 0) {
    #pragma unroll
    for (int o = 0; o < OUT_; ++o) red[wid][o] = acc[o];
  }
  __syncthreads();
  if (tid < OUT_) {
    float s = red[0][tid] + red[1][tid] + red[2][tid] + red[3][tid];
    part[((size_t)chunk*B_ + b)*OUT_ + tid] = s;
  }
}

__global__ __launch_bounds__(192)
void outred_k(const float* __restrict__ part, const float* __restrict__ bout,
              float* __restrict__ out)
{
  int t = threadIdx.x;
  if (t < B_*OUT_) {
    int b = t / OUT_, o = t % OUT_;
    float s = 0.f;
    for (int c = 0; c < 64; ++c) s += part[((size_t)c*B_ + b)*OUT_ + o];
    s += bout[o];
    out[t] = s;
  }
}

extern "C" void kernel_launch(void* const* d_in, const int* in_sizes, int n_in,
                              void* d_out, int out_size, void* d_ws, size_t ws_size,
                              hipStream_t stream)
{
  (void)out_size;
  float* outb = (float*)d_out;

  static const int expect[14] = {8192, 16384, 1048576, 1024, 1048576, 1024,
                                 1048576, 1024, 1048576, 1024, 1024, 1024,
                                 5242880, 10};
  if (n_in != 14) { code_k<<<dim3(1), dim3(192), 0, stream>>>(outb, 9000.0f); return; }
  for (int i = 0; i < 14; ++i)
    if (in_sizes[i] != expect[i]) {
      code_k<<<dim3(1), dim3(192), 0, stream>>>(outb, 5000.0f + 100.0f*i); return;
    }

  const int* tok = (const int*)d_in[0];
  const float* emb  = (const float*)d_in[1];
  const float* wq   = (const float*)d_in[2];
  const float* bq   = (const float*)d_in[3];
  const float* wk   = (const float*)d_in[4];
  const float* bk   = (const float*)d_in[5];
  const float* wv   = (const float*)d_in[6];
  const float* bv   = (const float*)d_in[7];
  const float* wfc  = (const float*)d_in[8];
  const float* bfc  = (const float*)d_in[9];
  const float* gam  = (const float*)d_in[10];
  const float* bet  = (const float*)d_in[11];
  const float* wout = (const float*)d_in[12];
  const float* bout = (const float*)d_in[13];

  char* ws = (char*)d_ws;
  size_t off = 0;
  unsigned short* wT = (unsigned short*)(ws + off); off += (size_t)4*E_*E_*2;
  unsigned short* x  = (unsigned short*)(ws + off); off += (size_t)M_*E_*2;
  unsigned short* qkvb = (unsigned short*)(ws + off); off += (size_t)3*M_*E_*2;
  unsigned short* gb = (unsigned short*)(ws + off); off += (size_t)M_*E_*2;
  float* part = (float*)(ws + off);                 off += (size_t)64*B_*OUT_*4;
  if (off > ws_size) { code_k<<<dim3(1), dim3(192), 0, stream>>>(outb, 9500.0f); return; }

  transpose_k<<<dim3(16,16,4), dim3(64,4), 0, stream>>>(wq, wk, wv, wfc, wT);
  embed_k<<<dim3(M_), dim3(256), 0, stream>>>(tok, emb, x);
  unsigned short* qb = qkvb;
  unsigned short* kb = qkvb + (size_t)M_*E_;
  unsigned short* vb = qkvb + (size_t)2*M_*E_;   // VT [B,H,D,S]
  for (int l = 0; l < NL_; ++l) {
    gemm_bt_k<0><<<dim3(64,16), dim3(256), 0, stream>>>(x, wT, bq, bk, qkvb);
    gemm_bt_k<2><<<dim3(64,8),  dim3(256), 0, stream>>>(x, wT + (size_t)2*E_*E_, bv, bv, vb);
    attn_k<<<dim3(1024), dim3(512), 43008, stream>>>(qb, kb, vb, gb);
    ln_k<true><<<dim3(M_/4), dim3(256), 0, stream>>>(gb, x, gam, bet);
    gemm_bt_k<1><<<dim3(64,8), dim3(256), 0, stream>>>(x, wT + (size_t)3*E_*E_, bfc, bfc, gb);
    ln_k<false><<<dim3(M_/4), dim3(256), 0, stream>>>(gb, x, gam, bet);
  }
  outp_k<<<dim3(64,B_), dim3(256), 0, stream>>>(x, wout, part);
  outred_k<<<dim3(1), dim3(192), 0, stream>>>(part, bout, outb);
}

// Round 23
// 969.431 us; speedup vs baseline: 1.0548x; 1.0548x over previous
//
#include <hip/hip_runtime.h>
#include <hip/hip_bf16.h>
#include <math.h>

#define B_   16
#define S_   512
#define E_   1024
#define H_   16
#define D_   64
#define NL_  6
#define OUT_ 10
#define M_   (B_*S_)

typedef short short8 __attribute__((ext_vector_type(8)));
typedef float f32x4 __attribute__((ext_vector_type(4)));
typedef int   int4v __attribute__((ext_vector_type(4)));
typedef unsigned short ushort4v __attribute__((ext_vector_type(4)));

typedef const __attribute__((address_space(1))) unsigned int* gas1_t;
typedef __attribute__((address_space(3))) unsigned int* las3_t;
#define GLD16(g,l) __builtin_amdgcn_global_load_lds((gas1_t)(g), (las3_t)(l), 16, 0, 0)

static __device__ __forceinline__ float bf2f(unsigned short u){
  union { unsigned int i; float f; } v; v.i = ((unsigned int)u) << 16; return v.f;
}
// native bf16 convert (RNE) — hw cvt on gfx950
static __device__ __forceinline__ unsigned short f2bf(float f){
  union { __hip_bfloat16 h; unsigned short u; } v;
  v.h = __float2bfloat16(f);
  return v.u;
}
static __device__ __forceinline__ f32x4 mfma16(short8 a, short8 b, f32x4 c){
  return __builtin_amdgcn_mfma_f32_16x16x32_bf16(a, b, c, 0, 0, 0);
}

// ---------------- code writer (f32 output) ----------------
__global__ __launch_bounds__(192)
void code_k(float* __restrict__ out, float code)
{
  int t = threadIdx.x;
  if (t < B_*OUT_) out[t] = code;
}

// ---------------- weight transpose + f32->bf16: wT[n][k] = bf16(w[k][n]) ----------------
__global__ __launch_bounds__(256)
void transpose_k(const float* __restrict__ w0, const float* __restrict__ w1,
                 const float* __restrict__ w2, const float* __restrict__ w3,
                 unsigned short* __restrict__ wT)
{
  const float* w = blockIdx.z==0 ? w0 : blockIdx.z==1 ? w1 : blockIdx.z==2 ? w2 : w3;
  unsigned short* o = wT + (size_t)blockIdx.z * E_ * E_;
  __shared__ unsigned short tl[64][65];
  int n0 = blockIdx.x*64, k0 = blockIdx.y*64;
  int tx = threadIdx.x, ty = threadIdx.y;
  #pragma unroll
  for (int i = 0; i < 16; ++i)
    tl[ty + 4*i][tx] = f2bf(w[(size_t)(k0 + ty + 4*i)*E_ + n0 + tx]);
  __syncthreads();
  #pragma unroll
  for (int i = 0; i < 16; ++i)
    o[(size_t)(n0 + ty + 4*i)*E_ + k0 + tx] = tl[tx][ty + 4*i];
}

// ---------------- embedding + positional: x = 2*emb[tok] + pe[b,e]; bf16 out ----------------
__global__ __launch_bounds__(256)
void embed_k(const int* __restrict__ tok, const float* __restrict__ emb,
             unsigned short* __restrict__ x)
{
  int row = blockIdx.x;            // b*512+s
  int b = row >> 9;
  int tk = tok[row];
  tk = tk < 0 ? 0 : (tk > 15 ? 15 : tk);
  int e0 = threadIdx.x * 4;
  const float c0 = -9.210340371976184f / (float)E_;   // -ln(10000)/E
  f32x4 ev = *(const f32x4*)&emb[(size_t)tk * E_ + e0];
  ushort4v bb;
  #pragma unroll
  for (int i = 0; i < 4; ++i) {
    int e = e0 + i;
    float dv = expf((float)(e & ~1) * c0);
    float arg = (float)b * dv;
    float pe = (e & 1) ? cosf(arg) : sinf(arg);
    bb[i] = f2bf(2.0f * ev[i] + pe);
  }
  *(ushort4v*)&x[(size_t)row*E_ + e0] = bb;
}

// ---------------- 128x128 bf16 MFMA GEMM, BT = [N][K], T2 XOR-swizzled LDS ----------------
// MODE 0: QK (grid.y=16): wsel=nyt>>3 (0=Q,1=K), writes bf16 [B,H,S,D] at outq+wsel*M*E
// MODE 2: V  (grid.y=8):  writes TRANSPOSED bf16 [B,H,D,S] at outq
// MODE 1: FC (grid.y=8):  writes bf16 [M][E] at outq
template<int MODE>
__global__ __launch_bounds__(256)
void gemm_bt_k(const unsigned short* __restrict__ A,
               const unsigned short* __restrict__ BT,
               const float* __restrict__ biasA, const float* __restrict__ biasB,
               unsigned short* __restrict__ outq)
{
  __shared__ alignas(16) unsigned short SM[(MODE==2) ? 17408 : 16384];
  unsigned short* Al = SM;
  unsigned short* Bl = SM + 8192;
  int mt = blockIdx.x;
  int nyt = blockIdx.y;
  int wsel = (MODE == 0) ? (nyt >> 3) : 0;
  int nt   = (MODE == 0) ? (nyt & 7) : nyt;
  const unsigned short* Bp = BT + (size_t)wsel * E_ * E_ + (size_t)nt * 128 * E_;
  const float* bias = (MODE == 0) ? (wsel == 0 ? biasA : biasB) : biasA;
  int tid = threadIdx.x;
  int lane = tid & 63, wid = tid >> 6;
  int wr = wid >> 1, wc = wid & 1;
  int m0 = mt * 128;
  int lr = lane & 15, lk = lane >> 4;
  int lx = lr & 7;
  int c8 = tid & 7;
  int rbase = tid >> 3;                  // r = j*32 + rbase
  int c8s = c8 ^ (rbase & 7);
  f32x4 acc[4][4] = {};
  for (int kt = 0; kt < E_/64; ++kt) {
    #pragma unroll
    for (int j = 0; j < 4; ++j) {
      int r = j*32 + rbase;
      int idx = j*256 + tid;
      GLD16(A + (size_t)(m0 + r)*E_ + kt*64 + c8s*8, &Al[idx*8]);
      GLD16(Bp + (size_t)r*E_ + kt*64 + c8s*8, &Bl[idx*8]);
    }
    __syncthreads();
    #pragma unroll
    for (int kk = 0; kk < 2; ++kk) {
      int sA = ((kk*4 + lk) ^ lx) * 8;
      short8 af[4], bfr[4];
      #pragma unroll
      for (int mi = 0; mi < 4; ++mi)
        af[mi] = *(const short8*)&Al[(wr*64 + mi*16 + lr)*64 + sA];
      #pragma unroll
      for (int ni = 0; ni < 4; ++ni)
        bfr[ni] = *(const short8*)&Bl[(wc*64 + ni*16 + lr)*64 + sA];
      #pragma unroll
      for (int mi = 0; mi < 4; ++mi)
        #pragma unroll
        for (int ni = 0; ni < 4; ++ni)
          acc[mi][ni] = mfma16(af[mi], bfr[ni], acc[mi][ni]);
    }
    __syncthreads();
  }
  if (MODE == 2) {
    unsigned short* Ct = SM;
    #pragma unroll
    for (int ni = 0; ni < 4; ++ni) {
      int nl = wc*64 + ni*16 + lr;
      float bv = bias[nt*128 + nl];
      #pragma unroll
      for (int mi = 0; mi < 4; ++mi)
        #pragma unroll
        for (int j = 0; j < 4; ++j)
          Ct[nl*136 + wr*64 + mi*16 + lk*4 + j] = f2bf(acc[mi][ni][j] + bv);
    }
    __syncthreads();
    int dl = tid >> 1, half = tid & 1;
    int h = nt*2 + (dl >> 6), d = dl & 63;
    int bb = m0 >> 9, s0 = (m0 & 511) + half*64;
    unsigned short* gp = outq + (((size_t)(bb*H_ + h)*D_ + d)*S_ + s0);
    #pragma unroll
    for (int c = 0; c < 8; ++c)
      *(int4v*)(gp + c*8) = *(const int4v*)&Ct[dl*136 + half*64 + c*8];
  } else {
    unsigned short* Cl = SM;
    #pragma unroll
    for (int ni = 0; ni < 4; ++ni) {
      int n = nt*128 + wc*64 + ni*16 + lr;
      float bv = bias[n];
      #pragma unroll
      for (int mi = 0; mi < 4; ++mi)
        #pragma unroll
        for (int j = 0; j < 4; ++j)
          Cl[(wr*64 + mi*16 + lk*4 + j)*128 + wc*64 + ni*16 + lr] =
            f2bf(acc[mi][ni][j] + bv);
    }
    __syncthreads();
    int r = tid >> 1, half = tid & 1;
    int m = m0 + r;
    unsigned short* gp;
    if (MODE == 0) {
      int bb = m >> 9, s = m & 511;
      int h = nt*2 + half;
      gp = outq + (size_t)wsel*M_*E_ + (((size_t)(bb*H_ + h)*S_ + s)*D_);
    } else {
      gp = outq + (size_t)m*E_ + nt*128 + half*64;
    }
    const unsigned short* sp = &Cl[r*128 + half*64];
    #pragma unroll
    for (int c = 0; c < 8; ++c)
      *(int4v*)(gp + c*8) = *(const int4v*)(sp + c*8);
  }
}

// ---------------- flash attention: kt-outer, K+V double-buffered in LDS (round-21 cfg + T5) ----------------
__global__ __launch_bounds__(512, 4)
void attn_k(const unsigned short* __restrict__ Q, const unsigned short* __restrict__ K,
            const unsigned short* __restrict__ VT, unsigned short* __restrict__ O)
{
  extern __shared__ unsigned short SMEM[];
  int bid = blockIdx.x;
  int bh = bid & 255, qh = bid >> 8;
  int tid = threadIdx.x, lane = tid & 63, wid = tid >> 6;
  int lr = lane & 15, lk = lane >> 4;
  const unsigned short* Qb = Q + (size_t)bh * S_ * D_;
  const unsigned short* Kb = K + (size_t)bh * S_ * D_;
  const unsigned short* VTb = VT + (size_t)bh * S_ * D_;
  unsigned short* Pw = SMEM + 32768 + wid * 640;

  int kr  = tid >> 3, kc8 = tid & 7;
  int kcs = kc8 ^ (kr & 7);
  short8 qf[2][2];
  #pragma unroll
  for (int s = 0; s < 2; ++s) {
    int q0 = (qh*2 + s)*128 + wid*16;
    qf[s][0] = *(const short8*)(Qb + (size_t)(q0 + lr)*D_ + lk*8);
    qf[s][1] = *(const short8*)(Qb + (size_t)(q0 + lr)*D_ + 32 + lk*8);
  }
  {
    unsigned short* Kd = SMEM;
    #pragma unroll
    for (int j = 0; j < 2; ++j) {
      int idx = j*512 + tid;
      GLD16(Kb + (size_t)(kr + j*64)*D_ + kcs*8, &Kd[idx*8]);
    }
  }
  {
    unsigned short* Vd = SMEM + 16384;
    #pragma unroll
    for (int j = 0; j < 2; ++j) {
      int idx = j*512 + tid;
      int d = idx >> 4, c16 = idx & 15;
      int cds = c16 ^ (d & 15);
      GLD16(VTb + (size_t)d*S_ + cds*8, &Vd[idx*8]);
    }
  }
  __syncthreads();

  f32x4 oacc[2][4] = {};
  float plsum[2][4] = {{0.f,0.f,0.f,0.f},{0.f,0.f,0.f,0.f}};
  int cur = 0;
  for (int kt = 0; kt < 4; ++kt) {
    if (kt < 3) {
      unsigned short* Kd = SMEM + (cur^1)*8192;
      unsigned short* Vd = SMEM + 16384 + (cur^1)*8192;
      #pragma unroll
      for (int j = 0; j < 2; ++j) {
        int idx = j*512 + tid;
        int r = idx >> 3, c8 = idx & 7;
        GLD16(Kb + (size_t)((kt+1)*128 + r)*D_ + (c8 ^ (r & 7))*8, &Kd[idx*8]);
        int d = idx >> 4, c16 = idx & 15;
        GLD16(VTb + (size_t)d*S_ + (kt+1)*128 + (c16 ^ (d & 15))*8, &Vd[idx*8]);
      }
    }
    const unsigned short* Kl = SMEM + cur*8192;
    const unsigned short* Vl = SMEM + 16384 + cur*8192;
    #pragma unroll
    for (int s = 0; s < 2; ++s) {
      #pragma unroll
      for (int c = 0; c < 4; ++c) {
        f32x4 s0 = {}, s1 = {};
        {
          const unsigned short* kr0 = &Kl[((2*c)*16 + lr)*64];
          const unsigned short* kr1 = &Kl[((2*c+1)*16 + lr)*64];
          int a0 = ((lk     ^ (lr & 7)))*8;
          int a1 = (((4+lk) ^ (lr & 7)))*8;
          __builtin_amdgcn_s_setprio(1);
          s0 = mfma16(qf[s][0], *(const short8*)(kr0 + a0), s0);
          s0 = mfma16(qf[s][1], *(const short8*)(kr0 + a1), s0);
          s1 = mfma16(qf[s][0], *(const short8*)(kr1 + a0), s1);
          s1 = mfma16(qf[s][1], *(const short8*)(kr1 + a1), s1);
          __builtin_amdgcn_s_setprio(0);
        }
        #pragma unroll
        for (int j = 0; j < 4; ++j) {
          s0[j] = __expf(s0[j] * 0.125f);
          s1[j] = __expf(s1[j] * 0.125f);
          plsum[s][j] += s0[j] + s1[j];
        }
        #pragma unroll
        for (int j = 0; j < 4; ++j) {
          Pw[(lk*4 + j)*40 + lr]      = f2bf(s0[j]);
          Pw[(lk*4 + j)*40 + 16 + lr] = f2bf(s1[j]);
        }
        asm volatile("s_waitcnt lgkmcnt(0)" ::: "memory");
        short8 pf = *(const short8*)&Pw[lr*40 + lk*8];
        __builtin_amdgcn_s_setprio(1);
        #pragma unroll
        for (int dt = 0; dt < 4; ++dt) {
          int drow = dt*16 + lr;
          short8 vf = *(const short8*)&Vl[drow*128 + (((c*4 + lk) ^ lr))*8];
          oacc[s][dt] = mfma16(pf, vf, oacc[s][dt]);
        }
        __builtin_amdgcn_s_setprio(0);
      }
    }
    __syncthreads();
    cur ^= 1;
  }
  #pragma unroll
  for (int s = 0; s < 2; ++s) {
    float lsum[4];
    #pragma unroll
    for (int j = 0; j < 4; ++j) {
      float t = plsum[s][j];
      #pragma unroll
      for (int m = 1; m < 16; m <<= 1) t += __shfl_xor(t, m);
      lsum[j] = t;
    }
    int q0 = (qh*2 + s)*128 + wid*16;
    #pragma unroll
    for (int dt = 0; dt < 4; ++dt)
      #pragma unroll
      for (int j = 0; j < 4; ++j)
        O[(size_t)bh*S_*D_ + (size_t)(q0 + lk*4 + j)*D_ + dt*16 + lr] =
          f2bf(oacc[s][dt][j] / lsum[j]);
  }
}

// ---------------- residual + layernorm: all-bf16 stream, f32 internal (round-21 cfg) ----------------
template<bool PERM>
__global__ __launch_bounds__(256)
void ln_k(const unsigned short* __restrict__ g, unsigned short* __restrict__ x,
          const float* __restrict__ gamma, const float* __restrict__ beta)
{
  int row = blockIdx.x;
  int tid = threadIdx.x;
  int e0 = tid * 4;
  ushort4v gu;
  if (PERM) {
    int b = row >> 9, s = row & 511;
    int h = e0 >> 6, d = e0 & 63;
    gu = *(const ushort4v*)&g[(((size_t)(b*H_ + h)*S_) + s)*D_ + d];
  } else {
    gu = *(const ushort4v*)&g[(size_t)row*E_ + e0];
  }
  ushort4v xu = *(const ushort4v*)&x[(size_t)row*E_ + e0];
  f32x4 v;
  #pragma unroll
  for (int i = 0; i < 4; ++i) v[i] = bf2f(gu[i]) + bf2f(xu[i]);
  float sum = v[0]+v[1]+v[2]+v[3];
  float sq  = v[0]*v[0]+v[1]*v[1]+v[2]*v[2]+v[3]*v[3];
  #pragma unroll
  for (int m = 1; m < 64; m <<= 1) { sum += __shfl_xor(sum, m); sq += __shfl_xor(sq, m); }
  __shared__ float red[2][4];
  int lane = tid & 63, wid = tid >> 6;
  if (lane == 0) { red[0][wid] = sum; red[1][wid] = sq; }
  __syncthreads();
  float ts = red[0][0]+red[0][1]+red[0][2]+red[0][3];
  float tq = red[1][0]+red[1][1]+red[1][2]+red[1][3];
  float mu = ts * (1.0f/E_);
  float var = tq * (1.0f/E_) - mu*mu;
  float rsq = rsqrtf(var + 1e-5f);
  ushort4v yb;
  #pragma unroll
  for (int i = 0; i < 4; ++i)
    yb[i] = f2bf((v[i]-mu)*rsq*gamma[e0+i] + beta[e0+i]);
  *(ushort4v*)&x[(size_t)row*E_ + e0] = yb;
}

// ---------------- output head (bf16 x input, f32 accum) ----------------
__global__ __launch_bounds__(256)
void outp_k(const unsigned short* __restrict__ x, const float* __restrict__ wout,
            float* __restrict__ part)
{
  int b = blockIdx.y;
  int chunk = blockIdx.x;
  int tid = threadIdx.x;
  float acc[OUT_] = {};
  const unsigned short* xr = x + (size_t)b * S_ * E_;
  for (int j = 0; j < 32; ++j) {
    int k = chunk*8192 + j*256 + tid;
    float xv = bf2f(xr[k]);
    const float* wr = wout + (size_t)k * OUT_;
    #pragma unroll
    for (int o = 0; o < OUT_; ++o) acc[o] += xv * wr[o];
  }
  #pragma unroll
  for (int o = 0; o < OUT_; ++o)
    #pragma unroll
    for (int m = 1; m < 64; m <<= 1) acc[o] += __shfl_xor(acc[o], m);
  __shared__ float red[4][OUT_];
  int lane = tid & 63, wid = tid >> 6;
  if (lane == 0) {
    #pragma unroll
    for (int o = 0; o < OUT_; ++o) red[wid][o] = acc[o];
  }
  __syncthreads();
  if (tid < OUT_) {
    float s = red[0][tid] + red[1][tid] + red[2][tid] + red[3][tid];
    part[((size_t)chunk*B_ + b)*OUT_ + tid] = s;
  }
}

__global__ __launch_bounds__(192)
void outred_k(const float* __restrict__ part, const float* __restrict__ bout,
              float* __restrict__ out)
{
  int t = threadIdx.x;
  if (t < B_*OUT_) {
    int b = t / OUT_, o = t % OUT_;
    float s = 0.f;
    for (int c = 0; c < 64; ++c) s += part[((size_t)c*B_ + b)*OUT_ + o];
    s += bout[o];
    out[t] = s;
  }
}

extern "C" void kernel_launch(void* const* d_in, const int* in_sizes, int n_in,
                              void* d_out, int out_size, void* d_ws, size_t ws_size,
                              hipStream_t stream)
{
  (void)out_size;
  float* outb = (float*)d_out;

  static const int expect[14] = {8192, 16384, 1048576, 1024, 1048576, 1024,
                                 1048576, 1024, 1048576, 1024, 1024, 1024,
                                 5242880, 10};
  if (n_in != 14) { code_k<<<dim3(1), dim3(192), 0, stream>>>(outb, 9000.0f); return; }
  for (int i = 0; i < 14; ++i)
    if (in_sizes[i] != expect[i]) {
      code_k<<<dim3(1), dim3(192), 0, stream>>>(outb, 5000.0f + 100.0f*i); return;
    }

  const int* tok = (const int*)d_in[0];
  const float* emb  = (const float*)d_in[1];
  const float* wq   = (const float*)d_in[2];
  const float* bq   = (const float*)d_in[3];
  const float* wk   = (const float*)d_in[4];
  const float* bk   = (const float*)d_in[5];
  const float* wv   = (const float*)d_in[6];
  const float* bv   = (const float*)d_in[7];
  const float* wfc  = (const float*)d_in[8];
  const float* bfc  = (const float*)d_in[9];
  const float* gam  = (const float*)d_in[10];
  const float* bet  = (const float*)d_in[11];
  const float* wout = (const float*)d_in[12];
  const float* bout = (const float*)d_in[13];

  char* ws = (char*)d_ws;
  size_t off = 0;
  unsigned short* wT = (unsigned short*)(ws + off); off += (size_t)4*E_*E_*2;
  unsigned short* x  = (unsigned short*)(ws + off); off += (size_t)M_*E_*2;
  unsigned short* qkvb = (unsigned short*)(ws + off); off += (size_t)3*M_*E_*2;
  unsigned short* gb = (unsigned short*)(ws + off); off += (size_t)M_*E_*2;
  float* part = (float*)(ws + off);                 off += (size_t)64*B_*OUT_*4;
  if (off > ws_size) { code_k<<<dim3(1), dim3(192), 0, stream>>>(outb, 9500.0f); return; }

  transpose_k<<<dim3(16,16,4), dim3(64,4), 0, stream>>>(wq, wk, wv, wfc, wT);
  embed_k<<<dim3(M_), dim3(256), 0, stream>>>(tok, emb, x);
  unsigned short* qb = qkvb;
  unsigned short* kb = qkvb + (size_t)M_*E_;
  unsigned short* vb = qkvb + (size_t)2*M_*E_;   // VT [B,H,D,S]
  for (int l = 0; l < NL_; ++l) {
    gemm_bt_k<0><<<dim3(64,16), dim3(256), 0, stream>>>(x, wT, bq, bk, qkvb);
    gemm_bt_k<2><<<dim3(64,8),  dim3(256), 0, stream>>>(x, wT + (size_t)2*E_*E_, bv, bv, vb);
    attn_k<<<dim3(512), dim3(512), 75776, stream>>>(qb, kb, vb, gb);
    ln_k<true><<<dim3(M_), dim3(256), 0, stream>>>(gb, x, gam, bet);
    gemm_bt_k<1><<<dim3(64,8), dim3(256), 0, stream>>>(x, wT + (size_t)3*E_*E_, bfc, bfc, gb);
    ln_k<false><<<dim3(M_), dim3(256), 0, stream>>>(gb, x, gam, bet);
  }
  outp_k<<<dim3(64,B_), dim3(256), 0, stream>>>(x, wout, part);
  outred_k<<<dim3(1), dim3(192), 0, stream>>>(part, bout, outb);
}

// Round 24
// 963.939 us; speedup vs baseline: 1.0608x; 1.0057x over previous
//
#include <hip/hip_runtime.h>
#include <hip/hip_bf16.h>
#include <math.h>

#define B_   16
#define S_   512
#define E_   1024
#define H_   16
#define D_   64
#define NL_  6
#define OUT_ 10
#define M_   (B_*S_)

typedef short short8 __attribute__((ext_vector_type(8)));
typedef float f32x4 __attribute__((ext_vector_type(4)));
typedef int   int4v __attribute__((ext_vector_type(4)));
typedef unsigned short ushort4v __attribute__((ext_vector_type(4)));

typedef const __attribute__((address_space(1))) unsigned int* gas1_t;
typedef __attribute__((address_space(3))) unsigned int* las3_t;
#define GLD16(g,l) __builtin_amdgcn_global_load_lds((gas1_t)(g), (las3_t)(l), 16, 0, 0)

static __device__ __forceinline__ float bf2f(unsigned short u){
  union { unsigned int i; float f; } v; v.i = ((unsigned int)u) << 16; return v.f;
}
// native bf16 convert (RNE) — hw cvt on gfx950
static __device__ __forceinline__ unsigned short f2bf(float f){
  union { __hip_bfloat16 h; unsigned short u; } v;
  v.h = __float2bfloat16(f);
  return v.u;
}
static __device__ __forceinline__ f32x4 mfma16(short8 a, short8 b, f32x4 c){
  return __builtin_amdgcn_mfma_f32_16x16x32_bf16(a, b, c, 0, 0, 0);
}

// ---------------- code writer (f32 output) ----------------
__global__ __launch_bounds__(192)
void code_k(float* __restrict__ out, float code)
{
  int t = threadIdx.x;
  if (t < B_*OUT_) out[t] = code;
}

// ---------------- weight transpose + f32->bf16: wT[n][k] = bf16(w[k][n]) ----------------
__global__ __launch_bounds__(256)
void transpose_k(const float* __restrict__ w0, const float* __restrict__ w1,
                 const float* __restrict__ w2, const float* __restrict__ w3,
                 unsigned short* __restrict__ wT)
{
  const float* w = blockIdx.z==0 ? w0 : blockIdx.z==1 ? w1 : blockIdx.z==2 ? w2 : w3;
  unsigned short* o = wT + (size_t)blockIdx.z * E_ * E_;
  __shared__ unsigned short tl[64][65];
  int n0 = blockIdx.x*64, k0 = blockIdx.y*64;
  int tx = threadIdx.x, ty = threadIdx.y;
  #pragma unroll
  for (int i = 0; i < 16; ++i)
    tl[ty + 4*i][tx] = f2bf(w[(size_t)(k0 + ty + 4*i)*E_ + n0 + tx]);
  __syncthreads();
  #pragma unroll
  for (int i = 0; i < 16; ++i)
    o[(size_t)(n0 + ty + 4*i)*E_ + k0 + tx] = tl[tx][ty + 4*i];
}

// ---------------- embedding + positional: x = 2*emb[tok] + pe[b,e]; bf16 out ----------------
__global__ __launch_bounds__(256)
void embed_k(const int* __restrict__ tok, const float* __restrict__ emb,
             unsigned short* __restrict__ x)
{
  int row = blockIdx.x;            // b*512+s
  int b = row >> 9;
  int tk = tok[row];
  tk = tk < 0 ? 0 : (tk > 15 ? 15 : tk);
  int e0 = threadIdx.x * 4;
  const float c0 = -9.210340371976184f / (float)E_;   // -ln(10000)/E
  f32x4 ev = *(const f32x4*)&emb[(size_t)tk * E_ + e0];
  ushort4v bb;
  #pragma unroll
  for (int i = 0; i < 4; ++i) {
    int e = e0 + i;
    float dv = expf((float)(e & ~1) * c0);
    float arg = (float)b * dv;
    float pe = (e & 1) ? cosf(arg) : sinf(arg);
    bb[i] = f2bf(2.0f * ev[i] + pe);
  }
  *(ushort4v*)&x[(size_t)row*E_ + e0] = bb;
}

// ---------------- 128x128 bf16 MFMA GEMM, BT = [N][K], T2 XOR-swizzled LDS ----------------
// MODE 0: QK (grid.y=16): wsel=nyt>>3 (0=Q,1=K), writes bf16 [B,H,S,D] at outq+wsel*M*E
// MODE 2: V  (grid.y=8):  writes TRANSPOSED bf16 [B,H,D,S] at outq
// MODE 1: FC (grid.y=8):  writes bf16 [M][E] at outq
template<int MODE>
__global__ __launch_bounds__(256)
void gemm_bt_k(const unsigned short* __restrict__ A,
               const unsigned short* __restrict__ BT,
               const float* __restrict__ biasA, const float* __restrict__ biasB,
               unsigned short* __restrict__ outq)
{
  __shared__ alignas(16) unsigned short SM[(MODE==2) ? 17408 : 16384];
  unsigned short* Al = SM;
  unsigned short* Bl = SM + 8192;
  int mt = blockIdx.x;
  int nyt = blockIdx.y;
  int wsel = (MODE == 0) ? (nyt >> 3) : 0;
  int nt   = (MODE == 0) ? (nyt & 7) : nyt;
  const unsigned short* Bp = BT + (size_t)wsel * E_ * E_ + (size_t)nt * 128 * E_;
  const float* bias = (MODE == 0) ? (wsel == 0 ? biasA : biasB) : biasA;
  int tid = threadIdx.x;
  int lane = tid & 63, wid = tid >> 6;
  int wr = wid >> 1, wc = wid & 1;
  int m0 = mt * 128;
  int lr = lane & 15, lk = lane >> 4;
  int lx = lr & 7;
  int c8 = tid & 7;
  int rbase = tid >> 3;                  // r = j*32 + rbase
  int c8s = c8 ^ (rbase & 7);
  f32x4 acc[4][4] = {};
  for (int kt = 0; kt < E_/64; ++kt) {
    #pragma unroll
    for (int j = 0; j < 4; ++j) {
      int r = j*32 + rbase;
      int idx = j*256 + tid;
      GLD16(A + (size_t)(m0 + r)*E_ + kt*64 + c8s*8, &Al[idx*8]);
      GLD16(Bp + (size_t)r*E_ + kt*64 + c8s*8, &Bl[idx*8]);
    }
    __syncthreads();
    #pragma unroll
    for (int kk = 0; kk < 2; ++kk) {
      int sA = ((kk*4 + lk) ^ lx) * 8;
      short8 af[4], bfr[4];
      #pragma unroll
      for (int mi = 0; mi < 4; ++mi)
        af[mi] = *(const short8*)&Al[(wr*64 + mi*16 + lr)*64 + sA];
      #pragma unroll
      for (int ni = 0; ni < 4; ++ni)
        bfr[ni] = *(const short8*)&Bl[(wc*64 + ni*16 + lr)*64 + sA];
      #pragma unroll
      for (int mi = 0; mi < 4; ++mi)
        #pragma unroll
        for (int ni = 0; ni < 4; ++ni)
          acc[mi][ni] = mfma16(af[mi], bfr[ni], acc[mi][ni]);
    }
    __syncthreads();
  }
  if (MODE == 2) {
    unsigned short* Ct = SM;
    #pragma unroll
    for (int ni = 0; ni < 4; ++ni) {
      int nl = wc*64 + ni*16 + lr;
      float bv = bias[nt*128 + nl];
      #pragma unroll
      for (int mi = 0; mi < 4; ++mi)
        #pragma unroll
        for (int j = 0; j < 4; ++j)
          Ct[nl*136 + wr*64 + mi*16 + lk*4 + j] = f2bf(acc[mi][ni][j] + bv);
    }
    __syncthreads();
    int dl = tid >> 1, half = tid & 1;
    int h = nt*2 + (dl >> 6), d = dl & 63;
    int bb = m0 >> 9, s0 = (m0 & 511) + half*64;
    unsigned short* gp = outq + (((size_t)(bb*H_ + h)*D_ + d)*S_ + s0);
    #pragma unroll
    for (int c = 0; c < 8; ++c)
      *(int4v*)(gp + c*8) = *(const int4v*)&Ct[dl*136 + half*64 + c*8];
  } else {
    unsigned short* Cl = SM;
    #pragma unroll
    for (int ni = 0; ni < 4; ++ni) {
      int n = nt*128 + wc*64 + ni*16 + lr;
      float bv = bias[n];
      #pragma unroll
      for (int mi = 0; mi < 4; ++mi)
        #pragma unroll
        for (int j = 0; j < 4; ++j)
          Cl[(wr*64 + mi*16 + lk*4 + j)*128 + wc*64 + ni*16 + lr] =
            f2bf(acc[mi][ni][j] + bv);
    }
    __syncthreads();
    int r = tid >> 1, half = tid & 1;
    int m = m0 + r;
    unsigned short* gp;
    if (MODE == 0) {
      int bb = m >> 9, s = m & 511;
      int h = nt*2 + half;
      gp = outq + (size_t)wsel*M_*E_ + (((size_t)(bb*H_ + h)*S_ + s)*D_);
    } else {
      gp = outq + (size_t)m*E_ + nt*128 + half*64;
    }
    const unsigned short* sp = &Cl[r*128 + half*64];
    #pragma unroll
    for (int c = 0; c < 8; ++c)
      *(int4v*)(gp + c*8) = *(const int4v*)(sp + c*8);
  }
}

// ---------------- flash attention: kt-outer, K+V double-buffered in LDS (round-21 cfg) ----------------
// O written ROW-MAJOR [B,S,E] (h-slice of the row) -> LN takes the sequential path.
__global__ __launch_bounds__(512, 4)
void attn_k(const unsigned short* __restrict__ Q, const unsigned short* __restrict__ K,
            const unsigned short* __restrict__ VT, unsigned short* __restrict__ O)
{
  extern __shared__ unsigned short SMEM[];
  int bid = blockIdx.x;
  int bh = bid & 255, qh = bid >> 8;
  int tid = threadIdx.x, lane = tid & 63, wid = tid >> 6;
  int lr = lane & 15, lk = lane >> 4;
  const unsigned short* Qb = Q + (size_t)bh * S_ * D_;
  const unsigned short* Kb = K + (size_t)bh * S_ * D_;
  const unsigned short* VTb = VT + (size_t)bh * S_ * D_;
  unsigned short* Pw = SMEM + 32768 + wid * 640;

  int kr  = tid >> 3, kc8 = tid & 7;
  int kcs = kc8 ^ (kr & 7);
  short8 qf[2][2];
  #pragma unroll
  for (int s = 0; s < 2; ++s) {
    int q0 = (qh*2 + s)*128 + wid*16;
    qf[s][0] = *(const short8*)(Qb + (size_t)(q0 + lr)*D_ + lk*8);
    qf[s][1] = *(const short8*)(Qb + (size_t)(q0 + lr)*D_ + 32 + lk*8);
  }
  {
    unsigned short* Kd = SMEM;
    #pragma unroll
    for (int j = 0; j < 2; ++j) {
      int idx = j*512 + tid;
      GLD16(Kb + (size_t)(kr + j*64)*D_ + kcs*8, &Kd[idx*8]);
    }
  }
  {
    unsigned short* Vd = SMEM + 16384;
    #pragma unroll
    for (int j = 0; j < 2; ++j) {
      int idx = j*512 + tid;
      int d = idx >> 4, c16 = idx & 15;
      int cds = c16 ^ (d & 15);
      GLD16(VTb + (size_t)d*S_ + cds*8, &Vd[idx*8]);
    }
  }
  __syncthreads();

  f32x4 oacc[2][4] = {};
  float plsum[2][4] = {{0.f,0.f,0.f,0.f},{0.f,0.f,0.f,0.f}};
  int cur = 0;
  for (int kt = 0; kt < 4; ++kt) {
    if (kt < 3) {
      unsigned short* Kd = SMEM + (cur^1)*8192;
      unsigned short* Vd = SMEM + 16384 + (cur^1)*8192;
      #pragma unroll
      for (int j = 0; j < 2; ++j) {
        int idx = j*512 + tid;
        int r = idx >> 3, c8 = idx & 7;
        GLD16(Kb + (size_t)((kt+1)*128 + r)*D_ + (c8 ^ (r & 7))*8, &Kd[idx*8]);
        int d = idx >> 4, c16 = idx & 15;
        GLD16(VTb + (size_t)d*S_ + (kt+1)*128 + (c16 ^ (d & 15))*8, &Vd[idx*8]);
      }
    }
    const unsigned short* Kl = SMEM + cur*8192;
    const unsigned short* Vl = SMEM + 16384 + cur*8192;
    #pragma unroll
    for (int s = 0; s < 2; ++s) {
      #pragma unroll
      for (int c = 0; c < 4; ++c) {
        f32x4 s0 = {}, s1 = {};
        {
          const unsigned short* kr0 = &Kl[((2*c)*16 + lr)*64];
          const unsigned short* kr1 = &Kl[((2*c+1)*16 + lr)*64];
          int a0 = ((lk     ^ (lr & 7)))*8;
          int a1 = (((4+lk) ^ (lr & 7)))*8;
          s0 = mfma16(qf[s][0], *(const short8*)(kr0 + a0), s0);
          s0 = mfma16(qf[s][1], *(const short8*)(kr0 + a1), s0);
          s1 = mfma16(qf[s][0], *(const short8*)(kr1 + a0), s1);
          s1 = mfma16(qf[s][1], *(const short8*)(kr1 + a1), s1);
        }
        #pragma unroll
        for (int j = 0; j < 4; ++j) {
          s0[j] = __expf(s0[j] * 0.125f);
          s1[j] = __expf(s1[j] * 0.125f);
          plsum[s][j] += s0[j] + s1[j];
        }
        #pragma unroll
        for (int j = 0; j < 4; ++j) {
          Pw[(lk*4 + j)*40 + lr]      = f2bf(s0[j]);
          Pw[(lk*4 + j)*40 + 16 + lr] = f2bf(s1[j]);
        }
        asm volatile("s_waitcnt lgkmcnt(0)" ::: "memory");
        short8 pf = *(const short8*)&Pw[lr*40 + lk*8];
        #pragma unroll
        for (int dt = 0; dt < 4; ++dt) {
          int drow = dt*16 + lr;
          short8 vf = *(const short8*)&Vl[drow*128 + (((c*4 + lk) ^ lr))*8];
          oacc[s][dt] = mfma16(pf, vf, oacc[s][dt]);
        }
      }
    }
    __syncthreads();
    cur ^= 1;
  }
  int bb = bh >> 4, h = bh & 15;
  #pragma unroll
  for (int s = 0; s < 2; ++s) {
    float lsum[4];
    #pragma unroll
    for (int j = 0; j < 4; ++j) {
      float t = plsum[s][j];
      #pragma unroll
      for (int m = 1; m < 16; m <<= 1) t += __shfl_xor(t, m);
      lsum[j] = t;
    }
    int q0 = (qh*2 + s)*128 + wid*16;
    #pragma unroll
    for (int dt = 0; dt < 4; ++dt)
      #pragma unroll
      for (int j = 0; j < 4; ++j) {
        int q = q0 + lk*4 + j;
        O[((size_t)(bb*S_ + q))*E_ + h*64 + dt*16 + lr] =
          f2bf(oacc[s][dt][j] / lsum[j]);
      }
  }
}

// ---------------- residual + layernorm: all-bf16 stream, f32 internal (sequential g) ----------------
__global__ __launch_bounds__(256)
void ln_k(const unsigned short* __restrict__ g, unsigned short* __restrict__ x,
          const float* __restrict__ gamma, const float* __restrict__ beta)
{
  int row = blockIdx.x;
  int tid = threadIdx.x;
  int e0 = tid * 4;
  ushort4v gu = *(const ushort4v*)&g[(size_t)row*E_ + e0];
  ushort4v xu = *(const ushort4v*)&x[(size_t)row*E_ + e0];
  f32x4 v;
  #pragma unroll
  for (int i = 0; i < 4; ++i) v[i] = bf2f(gu[i]) + bf2f(xu[i]);
  float sum = v[0]+v[1]+v[2]+v[3];
  float sq  = v[0]*v[0]+v[1]*v[1]+v[2]*v[2]+v[3]*v[3];
  #pragma unroll
  for (int m = 1; m < 64; m <<= 1) { sum += __shfl_xor(sum, m); sq += __shfl_xor(sq, m); }
  __shared__ float red[2][4];
  int lane = tid & 63, wid = tid >> 6;
  if (lane == 0) { red[0][wid] = sum; red[1][wid] = sq; }
  __syncthreads();
  float ts = red[0][0]+red[0][1]+red[0][2]+red[0][3];
  float tq = red[1][0]+red[1][1]+red[1][2]+red[1][3];
  float mu = ts * (1.0f/E_);
  float var = tq * (1.0f/E_) - mu*mu;
  float rsq = rsqrtf(var + 1e-5f);
  ushort4v yb;
  #pragma unroll
  for (int i = 0; i < 4; ++i)
    yb[i] = f2bf((v[i]-mu)*rsq*gamma[e0+i] + beta[e0+i]);
  *(ushort4v*)&x[(size_t)row*E_ + e0] = yb;
}

// ---------------- output head (bf16 x input, f32 accum) ----------------
__global__ __launch_bounds__(256)
void outp_k(const unsigned short* __restrict__ x, const float* __restrict__ wout,
            float* __restrict__ part)
{
  int b = blockIdx.y;
  int chunk = blockIdx.x;
  int tid = threadIdx.x;
  float acc[OUT_] = {};
  const unsigned short* xr = x + (size_t)b * S_ * E_;
  for (int j = 0; j < 32; ++j) {
    int k = chunk*8192 + j*256 + tid;
    float xv = bf2f(xr[k]);
    const float* wr = wout + (size_t)k * OUT_;
    #pragma unroll
    for (int o = 0; o < OUT_; ++o) acc[o] += xv * wr[o];
  }
  #pragma unroll
  for (int o = 0; o < OUT_; ++o)
    #pragma unroll
    for (int m = 1; m < 64; m <<= 1) acc[o] += __shfl_xor(acc[o], m);
  __shared__ float red[4][OUT_];
  int lane = tid & 63, wid = tid >> 6;
  if (lane == 0) {
    #pragma unroll
    for (int o = 0; o < OUT_; ++o) red[wid][o] = acc[o];
  }
  __syncthreads();
  if (tid < OUT_) {
    float s = red[0][tid] + red[1][tid] + red[2][tid] + red[3][tid];
    part[((size_t)chunk*B_ + b)*OUT_ + tid] = s;
  }
}

__global__ __launch_bounds__(192)
void outred_k(const float* __restrict__ part, const float* __restrict__ bout,
              float* __restrict__ out)
{
  int t = threadIdx.x;
  if (t < B_*OUT_) {
    int b = t / OUT_, o = t % OUT_;
    float s = 0.f;
    for (int c = 0; c < 64; ++c) s += part[((size_t)c*B_ + b)*OUT_ + o];
    s += bout[o];
    out[t] = s;
  }
}

extern "C" void kernel_launch(void* const* d_in, const int* in_sizes, int n_in,
                              void* d_out, int out_size, void* d_ws, size_t ws_size,
                              hipStream_t stream)
{
  (void)out_size;
  float* outb = (float*)d_out;

  static const int expect[14] = {8192, 16384, 1048576, 1024, 1048576, 1024,
                                 1048576, 1024, 1048576, 1024, 1024, 1024,
                                 5242880, 10};
  if (n_in != 14) { code_k<<<dim3(1), dim3(192), 0, stream>>>(outb, 9000.0f); return; }
  for (int i = 0; i < 14; ++i)
    if (in_sizes[i] != expect[i]) {
      code_k<<<dim3(1), dim3(192), 0, stream>>>(outb, 5000.0f + 100.0f*i); return;
    }

  const int* tok = (const int*)d_in[0];
  const float* emb  = (const float*)d_in[1];
  const float* wq   = (const float*)d_in[2];
  const float* bq   = (const float*)d_in[3];
  const float* wk   = (const float*)d_in[4];
  const float* bk   = (const float*)d_in[5];
  const float* wv   = (const float*)d_in[6];
  const float* bv   = (const float*)d_in[7];
  const float* wfc  = (const float*)d_in[8];
  const float* bfc  = (const float*)d_in[9];
  const float* gam  = (const float*)d_in[10];
  const float* bet  = (const float*)d_in[11];
  const float* wout = (const float*)d_in[12];
  const float* bout = (const float*)d_in[13];

  char* ws = (char*)d_ws;
  size_t off = 0;
  unsigned short* wT = (unsigned short*)(ws + off); off += (size_t)4*E_*E_*2;
  unsigned short* x  = (unsigned short*)(ws + off); off += (size_t)M_*E_*2;
  unsigned short* qkvb = (unsigned short*)(ws + off); off += (size_t)3*M_*E_*2;
  unsigned short* gb = (unsigned short*)(ws + off); off += (size_t)M_*E_*2;
  float* part = (float*)(ws + off);                 off += (size_t)64*B_*OUT_*4;
  if (off > ws_size) { code_k<<<dim3(1), dim3(192), 0, stream>>>(outb, 9500.0f); return; }

  transpose_k<<<dim3(16,16,4), dim3(64,4), 0, stream>>>(wq, wk, wv, wfc, wT);
  embed_k<<<dim3(M_), dim3(256), 0, stream>>>(tok, emb, x);
  unsigned short* qb = qkvb;
  unsigned short* kb = qkvb + (size_t)M_*E_;
  unsigned short* vb = qkvb + (size_t)2*M_*E_;   // VT [B,H,D,S]
  for (int l = 0; l < NL_; ++l) {
    gemm_bt_k<0><<<dim3(64,16), dim3(256), 0, stream>>>(x, wT, bq, bk, qkvb);
    gemm_bt_k<2><<<dim3(64,8),  dim3(256), 0, stream>>>(x, wT + (size_t)2*E_*E_, bv, bv, vb);
    attn_k<<<dim3(512), dim3(512), 75776, stream>>>(qb, kb, vb, gb);
    ln_k<<<dim3(M_), dim3(256), 0, stream>>>(gb, x, gam, bet);
    gemm_bt_k<1><<<dim3(64,8), dim3(256), 0, stream>>>(x, wT + (size_t)3*E_*E_, bfc, bfc, gb);
    ln_k<<<dim3(M_), dim3(256), 0, stream>>>(gb, x, gam, bet);
  }
  outp_k<<<dim3(64,B_), dim3(256), 0, stream>>>(x, wout, part);
  outred_k<<<dim3(1), dim3(192), 0, stream>>>(part, bout, outb);
}